// Round 1
// baseline (816.143 us; speedup 1.0000x reference)
//
#include <hip/hip_runtime.h>
#include <hip/hip_bf16.h>
#include <math.h>

typedef short short8 __attribute__((ext_vector_type(8)));
typedef float f32x4 __attribute__((ext_vector_type(4)));

#define CC 768
#define NN 1024
#define RR 32768
#define MM 512
#define ZSTRIDE 786432      // C*H*W
#define OUT_ATTN_OFF 25165824

static __device__ __forceinline__ short f2bf(float f) {
    __hip_bfloat16 h = __float2bfloat16(f);
    return *reinterpret_cast<short*>(&h);
}

// ---------------- Kernel A: memory norms + transposed copies ----------------
__global__ __launch_bounds__(256) void prep_mem_kernel(const float* __restrict__ memory,
                                                       float* __restrict__ mem_normT,
                                                       short* __restrict__ memT_bf) {
    int m = blockIdx.x;      // 0..511
    int t = threadIdx.x;
    double ss = 0.0;
    for (int c = t; c < CC; c += 256) {
        float v = memory[m * CC + c];
        ss += (double)v * (double)v;
    }
    #pragma unroll
    for (int off = 32; off > 0; off >>= 1) ss += __shfl_xor(ss, off);
    __shared__ double red[4];
    __shared__ double invs;
    if ((t & 63) == 0) red[t >> 6] = ss;
    __syncthreads();
    if (t == 0) {
        double tot = red[0] + red[1] + red[2] + red[3];
        invs = 1.0 / fmax(sqrt(tot), 1e-12);
    }
    __syncthreads();
    float inv = (float)invs;
    for (int c = t; c < CC; c += 256) {
        float v = memory[m * CC + c];
        mem_normT[c * MM + m] = v * inv;
        memT_bf[c * MM + m]   = f2bf(v);
    }
}

// ---------------- Kernel B: z row inverse norms (f64 accumulate) ----------------
__global__ __launch_bounds__(256) void znorm_kernel(const float* __restrict__ z,
                                                    double* __restrict__ zinv) {
    int row0 = blockIdx.x * 64;
    int b  = row0 >> 10;
    int n0 = row0 & 1023;
    int t  = threadIdx.x;
    int ln = t & 63, cg = t >> 6;
    const float* zb = z + (size_t)b * ZSTRIDE + n0 + ln;
    double ss = 0.0;
    for (int c = cg; c < CC; c += 4) {
        float v = zb[(size_t)c * NN];
        ss += (double)v * (double)v;
    }
    __shared__ double sm[256];
    sm[t] = ss;
    __syncthreads();
    if (t < 64) {
        double tot = sm[t] + sm[t + 64] + sm[t + 128] + sm[t + 192];
        zinv[row0 + t] = 1.0 / fmax(sqrt(tot), 1e-12);
    }
}

// ---------------- Kernel C: f32 scores GEMM + softmax + hardshrink + renorm ----------------
// Block: 64 rows x all 512 memory slots. 512 threads = 8 waves.
// Wave w owns rows w*8..w*8+7; lane tc owns cols {tc + 64*j}.
__global__ __launch_bounds__(512) void scores_attn_kernel(const float* __restrict__ z,
                                                          const float* __restrict__ mem_normT,
                                                          const double* __restrict__ zinv,
                                                          float* __restrict__ out_attn) {
    __shared__ float zt[16][64];     // k-major A tile
    __shared__ float bt[16][512];    // k-major B tile
    int t  = threadIdx.x;
    int tr = t >> 6;                 // wave id 0..7
    int tc = t & 63;                 // lane
    int row0 = blockIdx.x * 64;
    int b  = row0 >> 10;
    int n0 = row0 & 1023;

    float acc[8][8];
    #pragma unroll
    for (int i = 0; i < 8; ++i)
        #pragma unroll
        for (int j = 0; j < 8; ++j) acc[i][j] = 0.f;

    const float* zbase = z + (size_t)b * ZSTRIDE + n0;

    for (int c0 = 0; c0 < CC; c0 += 16) {
        __syncthreads();
        {   // stage z tile: 16 k x 64 rows (coalesced: 64 consecutive n per k)
            int kk = t >> 6, ln = t & 63;
            zt[kk][ln]     = zbase[(size_t)(c0 + kk) * NN + ln];
            zt[kk + 8][ln] = zbase[(size_t)(c0 + kk + 8) * NN + ln];
        }
        #pragma unroll
        for (int it = 0; it < 16; ++it) {   // stage mem tile: 16 k x 512 m
            bt[it][t] = mem_normT[(c0 + it) * MM + t];
        }
        __syncthreads();
        #pragma unroll
        for (int kk = 0; kk < 16; ++kk) {
            const f32x4* ap = reinterpret_cast<const f32x4*>(&zt[kk][tr * 8]);
            f32x4 a0 = ap[0], a1 = ap[1];
            float av[8] = {a0[0], a0[1], a0[2], a0[3], a1[0], a1[1], a1[2], a1[3]};
            #pragma unroll
            for (int j = 0; j < 8; ++j) {
                float bj = bt[kk][tc + (j << 6)];
                #pragma unroll
                for (int i = 0; i < 8; ++i) acc[i][j] = fmaf(av[i], bj, acc[i][j]);
            }
        }
    }

    // Epilogue in f64: one row of 512 scores lives in one wave (8 per lane).
    #pragma unroll 1
    for (int i = 0; i < 8; ++i) {
        int row = row0 + tr * 8 + i;
        double zi = zinv[row];
        double s[8];
        #pragma unroll
        for (int j = 0; j < 8; ++j) s[j] = (double)acc[i][j] * zi;
        double mx = s[0];
        #pragma unroll
        for (int j = 1; j < 8; ++j) mx = fmax(mx, s[j]);
        #pragma unroll
        for (int off = 32; off > 0; off >>= 1) mx = fmax(mx, __shfl_xor(mx, off));
        double p[8], Z = 0.0;
        #pragma unroll
        for (int j = 0; j < 8; ++j) { p[j] = exp(s[j] - mx); Z += p[j]; }
        #pragma unroll
        for (int off = 32; off > 0; off >>= 1) Z += __shfl_xor(Z, off);
        double a_[8], S = 0.0;
        #pragma unroll
        for (int j = 0; j < 8; ++j) {
            double w = p[j] / Z;
            double d = w - (1.0 / 512.0);
            double num = (d > 0.0 ? d : 0.0) * w;
            a_[j] = num / (fabs(d) + 1e-8);
            S += a_[j];
        }
        #pragma unroll
        for (int off = 32; off > 0; off >>= 1) S += __shfl_xor(S, off);
        double rinv = 1.0 / (S + 1e-8);
        #pragma unroll
        for (int j = 0; j < 8; ++j)
            out_attn[(size_t)row * MM + tc + (j << 6)] = (float)(a_[j] * rinv);
    }
}

// ---------------- Kernel D: z_hat = attn @ memory via bf16 MFMA ----------------
// Computes z_hat^T tiles: D[c][n] so stores into (B,C,H,W) are n-contiguous.
// A = memT (768 x 512, k=m contiguous), B = attn (32768 x 512, k=m contiguous): D = A*B^T.
__global__ __launch_bounds__(256) void readout_kernel(const short* __restrict__ memT_bf,
                                                      const float* __restrict__ attn,
                                                      float* __restrict__ out) {
    __shared__ short At[64][40];    // 64 c-rows x 32 k, padded to 40 (80B rows, 16B aligned)
    __shared__ short Bt[128][40];   // 128 n-rows x 32 k
    int t = threadIdx.x;
    int c0     = blockIdx.x * 64;
    int rowblk = blockIdx.y * 128;
    int b  = rowblk >> 10;
    int nb = rowblk & 1023;
    int lane = t & 63, wv = t >> 6;

    f32x4 acc[4][2];
    #pragma unroll
    for (int fc = 0; fc < 4; ++fc)
        #pragma unroll
        for (int fn = 0; fn < 2; ++fn) acc[fc][fn] = (f32x4){0.f, 0.f, 0.f, 0.f};

    for (int m0 = 0; m0 < MM; m0 += 32) {
        __syncthreads();
        {   // stage A: 64 x 32 bf16 (16B per thread)
            int r = t >> 2, ko = (t & 3) * 8;
            short8 v = *reinterpret_cast<const short8*>(&memT_bf[(c0 + r) * MM + m0 + ko]);
            *reinterpret_cast<short8*>(&At[r][ko]) = v;
        }
        {   // stage B: 128 x 32, converting attn f32 -> bf16 on the fly
            int r = t >> 1, ko = (t & 1) * 16;
            const float* src = &attn[(size_t)(rowblk + r) * MM + m0 + ko];
            #pragma unroll
            for (int q = 0; q < 16; ++q) Bt[r][ko + q] = f2bf(src[q]);
        }
        __syncthreads();
        short8 af[4], bfr[2];
        #pragma unroll
        for (int fc = 0; fc < 4; ++fc)
            af[fc] = *reinterpret_cast<const short8*>(&At[fc * 16 + (lane & 15)][(lane >> 4) * 8]);
        #pragma unroll
        for (int fn = 0; fn < 2; ++fn)
            bfr[fn] = *reinterpret_cast<const short8*>(&Bt[wv * 32 + fn * 16 + (lane & 15)][(lane >> 4) * 8]);
        #pragma unroll
        for (int fc = 0; fc < 4; ++fc)
            #pragma unroll
            for (int fn = 0; fn < 2; ++fn)
                acc[fc][fn] = __builtin_amdgcn_mfma_f32_16x16x32_bf16(af[fc], bfr[fn], acc[fc][fn], 0, 0, 0);
    }

    int cg = lane >> 4, cl = lane & 15;
    #pragma unroll
    for (int fc = 0; fc < 4; ++fc)
        #pragma unroll
        for (int fn = 0; fn < 2; ++fn)
            #pragma unroll
            for (int reg = 0; reg < 4; ++reg) {
                int c = c0 + fc * 16 + cg * 4 + reg;
                int n = nb + wv * 32 + fn * 16 + cl;
                out[(size_t)b * ZSTRIDE + (size_t)c * NN + n] = acc[fc][fn][reg];
            }
}

extern "C" void kernel_launch(void* const* d_in, const int* in_sizes, int n_in,
                              void* d_out, int out_size, void* d_ws, size_t ws_size,
                              hipStream_t stream) {
    const float* z      = (const float*)d_in[0];
    const float* memory = (const float*)d_in[1];
    float* out      = (float*)d_out;
    float* out_attn = out + OUT_ATTN_OFF;

    char* wsb = (char*)d_ws;
    float*  mem_normT = (float*)wsb;                  // 768*512*4  = 1572864 B
    short*  memT_bf   = (short*)(wsb + 1572864);      // 768*512*2  =  786432 B
    double* zinv      = (double*)(wsb + 2359296);     // 32768*8    =  262144 B

    prep_mem_kernel<<<512, 256, 0, stream>>>(memory, mem_normT, memT_bf);
    znorm_kernel<<<RR / 64, 256, 0, stream>>>(z, zinv);
    scores_attn_kernel<<<RR / 64, 512, 0, stream>>>(z, mem_normT, zinv, out_attn);
    readout_kernel<<<dim3(CC / 64, RR / 128), 256, 0, stream>>>(memT_bf, out_attn, out);
}

// Round 2
// 473.289 us; speedup vs baseline: 1.7244x; 1.7244x over previous
//
#include <hip/hip_runtime.h>
#include <hip/hip_bf16.h>
#include <math.h>

typedef short short8 __attribute__((ext_vector_type(8)));
typedef float f32x4 __attribute__((ext_vector_type(4)));

#define CC 768
#define NN 1024
#define RR 32768
#define MM 512
#define ZSTRIDE 786432      // C*H*W
#define OUT_ATTN_OFF 25165824

static __device__ __forceinline__ short f2bf(float f) {
    __hip_bfloat16 h = __float2bfloat16(f);
    return *reinterpret_cast<short*>(&h);
}

// async global->LDS DMA, 16B per lane
static __device__ __forceinline__ void gl_lds16(const float* g, float* l) {
    __builtin_amdgcn_global_load_lds(
        (const __attribute__((address_space(1))) void*)g,
        (__attribute__((address_space(3))) void*)l, 16, 0, 0);
}

// ---------------- Kernel A: memory norms + transposed copies ----------------
__global__ __launch_bounds__(256) void prep_mem_kernel(const float* __restrict__ memory,
                                                       float* __restrict__ mem_normT,
                                                       short* __restrict__ memT_bf) {
    int m = blockIdx.x;      // 0..511
    int t = threadIdx.x;
    double ss = 0.0;
    for (int c = t; c < CC; c += 256) {
        float v = memory[m * CC + c];
        ss += (double)v * (double)v;
    }
    #pragma unroll
    for (int off = 32; off > 0; off >>= 1) ss += __shfl_xor(ss, off);
    __shared__ double red[4];
    __shared__ double invs;
    if ((t & 63) == 0) red[t >> 6] = ss;
    __syncthreads();
    if (t == 0) {
        double tot = red[0] + red[1] + red[2] + red[3];
        invs = 1.0 / fmax(sqrt(tot), 1e-12);
    }
    __syncthreads();
    float inv = (float)invs;
    for (int c = t; c < CC; c += 256) {
        float v = memory[m * CC + c];
        mem_normT[c * MM + m] = v * inv;
        memT_bf[c * MM + m]   = f2bf(v);
    }
}

// ---------------- Kernel B: z row inverse norms (f64 accumulate) ----------------
__global__ __launch_bounds__(256) void znorm_kernel(const float* __restrict__ z,
                                                    double* __restrict__ zinv) {
    int row0 = blockIdx.x * 64;
    int b  = row0 >> 10;
    int n0 = row0 & 1023;
    int t  = threadIdx.x;
    int ln = t & 63, cg = t >> 6;
    const float* zb = z + (size_t)b * ZSTRIDE + n0 + ln;
    double ss = 0.0;
    for (int c = cg; c < CC; c += 4) {
        float v = zb[(size_t)c * NN];
        ss += (double)v * (double)v;
    }
    __shared__ double sm[256];
    sm[t] = ss;
    __syncthreads();
    if (t < 64) {
        double tot = sm[t] + sm[t + 64] + sm[t + 128] + sm[t + 192];
        zinv[row0 + t] = 1.0 / fmax(sqrt(tot), 1e-12);
    }
}

// ---------------- Kernel C: f32 scores GEMM + softmax + hardshrink + renorm ----------------
// Block: 64 rows x 512 cols, 256 threads = 4 waves.
// Wave tr owns rows tr*16..tr*16+15 (16 rows/thread).
// Lane tc owns cols {tc*4+j, 256+tc*4+j : j=0..3}  (8 cols/thread, b128-friendly).
__global__ __launch_bounds__(256, 2) void scores_attn_kernel(const float* __restrict__ z,
                                                             const float* __restrict__ mem_normT,
                                                             const double* __restrict__ zinv,
                                                             float* __restrict__ out_attn) {
    __shared__ float zt[2][16][64];      // 2 x 4KB
    __shared__ float bt[2][16][512];     // 2 x 32KB
    int t  = threadIdx.x;
    int tr = t >> 6;                 // wave id 0..3
    int tc = t & 63;                 // lane
    int row0 = blockIdx.x * 64;
    int b  = row0 >> 10;
    int n0 = row0 & 1023;

    const float* zbase = z + (size_t)b * ZSTRIDE + n0;

    // DMA-staging per-lane source offsets (wave-uniform LDS bases)
    int kz = tr * 4 + (tc >> 4);           // zt row this lane feeds
    int cz = (tc & 15) * 4;                // zt col
    float* zt_dst0 = &zt[0][0][0] + tr * 256;   // + lane*4 floats by HW
    float* bt_dst0 = &bt[0][0][0];

    float acc[16][8];
    #pragma unroll
    for (int i = 0; i < 16; ++i)
        #pragma unroll
        for (int j = 0; j < 8; ++j) acc[i][j] = 0.f;

    // ---- stage tile 0 ----
    {
        gl_lds16(zbase + (size_t)kz * NN + cz, zt_dst0);
        #pragma unroll
        for (int q = 0; q < 8; ++q) {
            int ci = q * 4 + tr;                       // chunk 0..31
            int kb = ci >> 1;
            int m  = (ci & 1) * 256 + tc * 4;
            gl_lds16(mem_normT + kb * MM + m, bt_dst0 + ci * 256);
        }
    }
    __syncthreads();

    int cur = 0;
    for (int step = 0; step < CC / 16; ++step) {
        int c0n = (step + 1) * 16;
        if (step + 1 < CC / 16) {   // stage next tile into buf cur^1
            int nb = cur ^ 1;
            gl_lds16(zbase + (size_t)(c0n + kz) * NN + cz,
                     &zt[nb][0][0] + tr * 256);
            #pragma unroll
            for (int q = 0; q < 8; ++q) {
                int ci = q * 4 + tr;
                int kb = ci >> 1;
                int m  = (ci & 1) * 256 + tc * 4;
                gl_lds16(mem_normT + (c0n + kb) * MM + m,
                         &bt[nb][0][0] + ci * 256);
            }
        }
        // compute on buf cur
        #pragma unroll 8
        for (int kk = 0; kk < 16; ++kk) {
            f32x4 b0 = *reinterpret_cast<const f32x4*>(&bt[cur][kk][tc * 4]);
            f32x4 b1 = *reinterpret_cast<const f32x4*>(&bt[cur][kk][256 + tc * 4]);
            f32x4 a0 = *reinterpret_cast<const f32x4*>(&zt[cur][kk][tr * 16 + 0]);
            f32x4 a1 = *reinterpret_cast<const f32x4*>(&zt[cur][kk][tr * 16 + 4]);
            f32x4 a2 = *reinterpret_cast<const f32x4*>(&zt[cur][kk][tr * 16 + 8]);
            f32x4 a3 = *reinterpret_cast<const f32x4*>(&zt[cur][kk][tr * 16 + 12]);
            float av[16] = {a0[0],a0[1],a0[2],a0[3], a1[0],a1[1],a1[2],a1[3],
                            a2[0],a2[1],a2[2],a2[3], a3[0],a3[1],a3[2],a3[3]};
            float bv[8]  = {b0[0],b0[1],b0[2],b0[3], b1[0],b1[1],b1[2],b1[3]};
            #pragma unroll
            for (int i = 0; i < 16; ++i)
                #pragma unroll
                for (int j = 0; j < 8; ++j)
                    acc[i][j] = fmaf(av[i], bv[j], acc[i][j]);
        }
        __syncthreads();   // emits vmcnt(0): staged DMA for cur^1 complete
        cur ^= 1;
    }

    // ---- epilogue, f64, fully unrolled (static acc indices!) ----
    #pragma unroll
    for (int i = 0; i < 16; ++i) {
        int row = row0 + tr * 16 + i;
        double zi = zinv[row];
        double s0 = (double)acc[i][0] * zi, s1 = (double)acc[i][1] * zi;
        double s2 = (double)acc[i][2] * zi, s3 = (double)acc[i][3] * zi;
        double s4 = (double)acc[i][4] * zi, s5 = (double)acc[i][5] * zi;
        double s6 = (double)acc[i][6] * zi, s7 = (double)acc[i][7] * zi;
        double mx = fmax(fmax(fmax(s0, s1), fmax(s2, s3)),
                         fmax(fmax(s4, s5), fmax(s6, s7)));
        #pragma unroll
        for (int off = 32; off > 0; off >>= 1) mx = fmax(mx, __shfl_xor(mx, off));
        double p0 = exp(s0 - mx), p1 = exp(s1 - mx), p2 = exp(s2 - mx), p3 = exp(s3 - mx);
        double p4 = exp(s4 - mx), p5 = exp(s5 - mx), p6 = exp(s6 - mx), p7 = exp(s7 - mx);
        double Z = ((p0 + p1) + (p2 + p3)) + ((p4 + p5) + (p6 + p7));
        #pragma unroll
        for (int off = 32; off > 0; off >>= 1) Z += __shfl_xor(Z, off);
        double iZ = 1.0 / Z;
        const double lam = 1.0 / 512.0;
        double w0 = p0 * iZ, w1 = p1 * iZ, w2 = p2 * iZ, w3 = p3 * iZ;
        double w4 = p4 * iZ, w5 = p5 * iZ, w6 = p6 * iZ, w7 = p7 * iZ;
        double d0 = w0 - lam, d1 = w1 - lam, d2 = w2 - lam, d3 = w3 - lam;
        double d4 = w4 - lam, d5 = w5 - lam, d6 = w6 - lam, d7 = w7 - lam;
        double e0 = (d0 > 0.0 ? d0 : 0.0) * w0 / (fabs(d0) + 1e-8);
        double e1 = (d1 > 0.0 ? d1 : 0.0) * w1 / (fabs(d1) + 1e-8);
        double e2 = (d2 > 0.0 ? d2 : 0.0) * w2 / (fabs(d2) + 1e-8);
        double e3 = (d3 > 0.0 ? d3 : 0.0) * w3 / (fabs(d3) + 1e-8);
        double e4 = (d4 > 0.0 ? d4 : 0.0) * w4 / (fabs(d4) + 1e-8);
        double e5 = (d5 > 0.0 ? d5 : 0.0) * w5 / (fabs(d5) + 1e-8);
        double e6 = (d6 > 0.0 ? d6 : 0.0) * w6 / (fabs(d6) + 1e-8);
        double e7 = (d7 > 0.0 ? d7 : 0.0) * w7 / (fabs(d7) + 1e-8);
        double S = ((e0 + e1) + (e2 + e3)) + ((e4 + e5) + (e6 + e7));
        #pragma unroll
        for (int off = 32; off > 0; off >>= 1) S += __shfl_xor(S, off);
        double rinv = 1.0 / (S + 1e-8);
        f32x4 o0 = { (float)(e0 * rinv), (float)(e1 * rinv),
                     (float)(e2 * rinv), (float)(e3 * rinv) };
        f32x4 o1 = { (float)(e4 * rinv), (float)(e5 * rinv),
                     (float)(e6 * rinv), (float)(e7 * rinv) };
        *reinterpret_cast<f32x4*>(&out_attn[(size_t)row * MM + tc * 4])       = o0;
        *reinterpret_cast<f32x4*>(&out_attn[(size_t)row * MM + 256 + tc * 4]) = o1;
    }
}

// ---------------- Kernel D: z_hat = attn @ memory via bf16 MFMA ----------------
__global__ __launch_bounds__(256) void readout_kernel(const short* __restrict__ memT_bf,
                                                      const float* __restrict__ attn,
                                                      float* __restrict__ out) {
    __shared__ short At[64][40];    // 64 c-rows x 32 k, padded
    __shared__ short Bt[128][40];   // 128 n-rows x 32 k
    int t = threadIdx.x;
    int c0     = blockIdx.x * 64;
    int rowblk = blockIdx.y * 128;
    int b  = rowblk >> 10;
    int nb = rowblk & 1023;
    int lane = t & 63, wv = t >> 6;

    f32x4 acc[4][2];
    #pragma unroll
    for (int fc = 0; fc < 4; ++fc)
        #pragma unroll
        for (int fn = 0; fn < 2; ++fn) acc[fc][fn] = (f32x4){0.f, 0.f, 0.f, 0.f};

    for (int m0 = 0; m0 < MM; m0 += 32) {
        __syncthreads();
        {   // stage A: 64 x 32 bf16
            int r = t >> 2, ko = (t & 3) * 8;
            short8 v = *reinterpret_cast<const short8*>(&memT_bf[(c0 + r) * MM + m0 + ko]);
            *reinterpret_cast<short8*>(&At[r][ko]) = v;
        }
        {   // stage B: 128 x 32, converting attn f32 -> bf16
            int r = t >> 1, ko = (t & 1) * 16;
            const float* src = &attn[(size_t)(rowblk + r) * MM + m0 + ko];
            #pragma unroll
            for (int q = 0; q < 16; ++q) Bt[r][ko + q] = f2bf(src[q]);
        }
        __syncthreads();
        short8 af[4], bfr[2];
        #pragma unroll
        for (int fc = 0; fc < 4; ++fc)
            af[fc] = *reinterpret_cast<const short8*>(&At[fc * 16 + (lane & 15)][(lane >> 4) * 8]);
        #pragma unroll
        for (int fn = 0; fn < 2; ++fn)
            bfr[fn] = *reinterpret_cast<const short8*>(&Bt[wv * 32 + fn * 16 + (lane & 15)][(lane >> 4) * 8]);
        #pragma unroll
        for (int fc = 0; fc < 4; ++fc)
            #pragma unroll
            for (int fn = 0; fn < 2; ++fn)
                acc[fc][fn] = __builtin_amdgcn_mfma_f32_16x16x32_bf16(af[fc], bfr[fn], acc[fc][fn], 0, 0, 0);
    }

    int cg = lane >> 4, cl = lane & 15;
    #pragma unroll
    for (int fc = 0; fc < 4; ++fc)
        #pragma unroll
        for (int fn = 0; fn < 2; ++fn)
            #pragma unroll
            for (int reg = 0; reg < 4; ++reg) {
                int c = c0 + fc * 16 + cg * 4 + reg;
                int n = nb + wv * 32 + fn * 16 + cl;
                out[(size_t)b * ZSTRIDE + (size_t)c * NN + n] = acc[fc][fn][reg];
            }
}

extern "C" void kernel_launch(void* const* d_in, const int* in_sizes, int n_in,
                              void* d_out, int out_size, void* d_ws, size_t ws_size,
                              hipStream_t stream) {
    const float* z      = (const float*)d_in[0];
    const float* memory = (const float*)d_in[1];
    float* out      = (float*)d_out;
    float* out_attn = out + OUT_ATTN_OFF;

    char* wsb = (char*)d_ws;
    float*  mem_normT = (float*)wsb;                  // 768*512*4  = 1572864 B
    short*  memT_bf   = (short*)(wsb + 1572864);      // 768*512*2  =  786432 B
    double* zinv      = (double*)(wsb + 2359296);     // 32768*8    =  262144 B

    prep_mem_kernel<<<512, 256, 0, stream>>>(memory, mem_normT, memT_bf);
    znorm_kernel<<<RR / 64, 256, 0, stream>>>(z, zinv);
    scores_attn_kernel<<<RR / 64, 256, 0, stream>>>(z, mem_normT, zinv, out_attn);
    readout_kernel<<<dim3(CC / 64, RR / 128), 256, 0, stream>>>(memT_bf, out_attn, out);
}